// Round 5
// baseline (270.314 us; speedup 1.0000x reference)
//
#include <hip/hip_runtime.h>
#include <hip/hip_cooperative_groups.h>

// Fused attention block: B=4, S=2048, F=512, D=64
//  q = x@Wq + bq ; k = x@Wk + bk ; v = x@Wv + bv      (B,S,D)
//  logits = q@k^T / 8 + (1-mask)*-1e9 ; attn = softmax ; out = attn@v
//
// R5: cooperative mega-kernel, re-sized to pass the co-residency check that
// rejected R4: grid 512 x 256thr (4 waves), launch_bounds(256,4) => VGPR<=128,
// LDS 26.4KB => 2 blocks/CU even under the conservative 64KB/CU occupancy
// assumption (52.7KB in R4 gave 1 block/CU -> 512 > 256 -> launch rejected).
// Return code is now CHECKED; on failure fall back to the proven R3 3-kernel
// path (65.6us).
//
// MFMA v_mfma_f32_16x16x32_bf16 fragment layouts (guide §3, m89/m91):
//   A: lane holds A[row = lane&15][k = (lane>>4)*8 + e], e=0..7
//   B: lane holds B[k = (lane>>4)*8 + e][col = lane&15]
//   C/D: lane holds D[row = (lane>>4)*4 + r][col = lane&15], r=0..3

typedef __attribute__((ext_vector_type(8))) short bhalf8;
typedef __attribute__((ext_vector_type(4))) float fx4;

#define MFMA(a, b, c) __builtin_amdgcn_mfma_f32_16x16x32_bf16((a), (b), (c), 0, 0, 0)

__device__ __forceinline__ short f2bf(float f) {
    union { float f; unsigned u; } v; v.f = f;
    unsigned r = (v.u + 0x7FFFu + ((v.u >> 16) & 1u)) >> 16;  // RNE
    return (short)r;
}

// ======================= cooperative mega-kernel ===========================
__global__ __launch_bounds__(256, 4) void mega_kernel(
    const float* __restrict__ x,  const int* __restrict__ mask,
    const float* __restrict__ Wq, const float* __restrict__ bq,
    const float* __restrict__ Wk, const float* __restrict__ bk,
    const float* __restrict__ Wv, const float* __restrict__ bv,
    short* __restrict__ Wt, short* __restrict__ Qb,
    short* __restrict__ Kb, short* __restrict__ Vt,
    float* __restrict__ out)
{
    cooperative_groups::grid_group grid = cooperative_groups::this_grid();
    const int tid  = threadIdx.x;
    const int lane = tid & 63;
    const int w4   = tid >> 6;          // wave id 0..3
    const int g = lane >> 4, c = lane & 15;

    __shared__ float olds[4][16][65];   // 16640 B (pad 65: no bank clash)
    __shared__ float mlds[4][16];       //   256 B
    __shared__ float llds[4][16];       //   256 B
    __shared__ short Plds[4][16][72];   //  9216 B (pad 72: 16B-aligned rows)

    // ---- Phase W: W[F][D] f32 -> Wt[3][64][512] bf16 (transposed) ----
    {
        const int gtid = blockIdx.x * 256 + tid;      // 0..131071
        if (gtid < 3 * 64 * 512) {
            const int m = gtid >> 15, rem = gtid & 32767;
            const int d = rem >> 9, k = rem & 511;
            const float* W = (m == 0) ? Wq : (m == 1) ? Wk : Wv;
            Wt[gtid] = f2bf(W[k * 64 + d]);
        }
    }
    __threadfence();
    grid.sync();

    // ---- Phase P: QKV projection; unit = (16 rows, 1 matrix), full K ----
    {
        const int uid = blockIdx.x * 4 + w4;          // 0..2047, 1536 active
        if (uid < 1536) {
            const int mat = uid % 3;
            const int rowbase = (uid / 3) * 16;
            const float* xrow = x + (size_t)(rowbase + c) * 512;   // A row = lane&15
            const short* Wm = Wt + (size_t)mat * 64 * 512;

            fx4 acc[4];
#pragma unroll
            for (int t = 0; t < 4; ++t) acc[t] = (fx4){0.f, 0.f, 0.f, 0.f};

#pragma unroll 4
            for (int ks = 0; ks < 16; ++ks) {
                const int k0 = ks * 32 + g * 8;
                const float4 x0 = *(const float4*)(xrow + k0);
                const float4 x1 = *(const float4*)(xrow + k0 + 4);
                bhalf8 a;
                a[0] = f2bf(x0.x); a[1] = f2bf(x0.y); a[2] = f2bf(x0.z); a[3] = f2bf(x0.w);
                a[4] = f2bf(x1.x); a[5] = f2bf(x1.y); a[6] = f2bf(x1.z); a[7] = f2bf(x1.w);
#pragma unroll
                for (int t = 0; t < 4; ++t) {
                    const bhalf8 bf = *(const bhalf8*)(Wm + (size_t)(t * 16 + c) * 512 + k0);
                    acc[t] = MFMA(a, bf, acc[t]);
                }
            }

            const float* bias = (mat == 0) ? bq : (mat == 1) ? bk : bv;
#pragma unroll
            for (int t = 0; t < 4; ++t) {
                const int col = t * 16 + c;
                const float bv_ = bias[col];
#pragma unroll
                for (int r = 0; r < 4; ++r) {
                    const int row = rowbase + g * 4 + r;   // D row = (lane>>4)*4+r
                    const short hv = f2bf(acc[t][r] + bv_);
                    if (mat == 0)      Qb[row * 64 + col] = hv;
                    else if (mat == 1) Kb[row * 64 + col] = hv;
                    else               Vt[((size_t)(row >> 11) * 64 + col) * 2048 + (row & 2047)] = hv;
                }
            }
        }
    }
    __threadfence();
    grid.sync();

    // ---- Phase A: flash attention; 4 waves x 512-key slices, LDS combine ----
    {
        const int wid   = w4;
        const int b     = blockIdx.x >> 7;
        const int qbase = (blockIdx.x & 127) << 4;
        const short* Qp = Qb + (size_t)(b * 2048 + qbase) * 64;
        const short* Kp = Kb + (size_t)b * 2048 * 64;
        const short* Vp = Vt + (size_t)b * 64 * 2048;
        const int*   mp = mask + b * 2048;

        const bhalf8 qf0 = *(const bhalf8*)(Qp + c * 64 + g * 8);
        const bhalf8 qf1 = *(const bhalf8*)(Qp + c * 64 + 32 + g * 8);

        float m_r[4], l_r[4];
        fx4 o[4];
#pragma unroll
        for (int r = 0; r < 4; ++r) { m_r[r] = -1e30f; l_r[r] = 0.f; }
#pragma unroll
        for (int dt = 0; dt < 4; ++dt) o[dt] = (fx4){0.f, 0.f, 0.f, 0.f};

        for (int kt = 0; kt < 8; ++kt) {
            const int kb = (wid * 8 + kt) * 64;
            // QK^T: four 16-key n-tiles, K=64
            fx4 s[4];
#pragma unroll
            for (int t = 0; t < 4; ++t) {
                const short* kp = Kp + (size_t)(kb + t * 16 + c) * 64 + g * 8;
                const bhalf8 kf0 = *(const bhalf8*)(kp);
                const bhalf8 kf1 = *(const bhalf8*)(kp + 32);
                fx4 z = (fx4){0.f, 0.f, 0.f, 0.f};
                z = MFMA(qf0, kf0, z);
                s[t] = MFMA(qf1, kf1, z);
            }
            // mask + scale; online softmax (rows g*4+r, cols c+16t)
            float madd[4];
#pragma unroll
            for (int t = 0; t < 4; ++t) madd[t] = mp[kb + t * 16 + c] ? 0.f : -1e9f;
            float p[4][4], tm[4];
#pragma unroll
            for (int r = 0; r < 4; ++r) {
                tm[r] = -1e30f;
#pragma unroll
                for (int t = 0; t < 4; ++t) {
                    p[t][r] = s[t][r] * 0.125f + madd[t];
                    tm[r] = fmaxf(tm[r], p[t][r]);
                }
            }
#pragma unroll
            for (int r = 0; r < 4; ++r) {
                tm[r] = fmaxf(tm[r], __shfl_xor(tm[r], 1));
                tm[r] = fmaxf(tm[r], __shfl_xor(tm[r], 2));
                tm[r] = fmaxf(tm[r], __shfl_xor(tm[r], 4));
                tm[r] = fmaxf(tm[r], __shfl_xor(tm[r], 8));
            }
            float fac[4];
#pragma unroll
            for (int r = 0; r < 4; ++r) {
                const float nm = fmaxf(m_r[r], tm[r]);
                fac[r] = __expf(m_r[r] - nm);
                m_r[r] = nm;
                float rs = 0.f;
#pragma unroll
                for (int t = 0; t < 4; ++t) {
                    p[t][r] = __expf(p[t][r] - nm);
                    rs += p[t][r];
                }
                rs += __shfl_xor(rs, 1);
                rs += __shfl_xor(rs, 2);
                rs += __shfl_xor(rs, 4);
                rs += __shfl_xor(rs, 8);
                l_r[r] = l_r[r] * fac[r] + rs;
            }
#pragma unroll
            for (int dt = 0; dt < 4; ++dt)
#pragma unroll
                for (int r = 0; r < 4; ++r) o[dt][r] *= fac[r];

            // P -> LDS (re-fragment for PV A-operand); intra-wave only
            asm volatile("" ::: "memory");
#pragma unroll
            for (int t = 0; t < 4; ++t)
#pragma unroll
                for (int r = 0; r < 4; ++r)
                    Plds[wid][g * 4 + r][t * 16 + c] = f2bf(p[t][r]);
            asm volatile("s_waitcnt lgkmcnt(0)" ::: "memory");
            const bhalf8 pa0 = *(const bhalf8*)(&Plds[wid][c][g * 8]);
            const bhalf8 pa1 = *(const bhalf8*)(&Plds[wid][c][32 + g * 8]);
#pragma unroll
            for (int dt = 0; dt < 4; ++dt) {
                const short* vp = Vp + (size_t)(dt * 16 + c) * 2048 + kb + g * 8;
                const bhalf8 vf0 = *(const bhalf8*)(vp);
                const bhalf8 vf1 = *(const bhalf8*)(vp + 32);
                o[dt] = MFMA(pa0, vf0, o[dt]);
                o[dt] = MFMA(pa1, vf1, o[dt]);
            }
        }

        // publish per-wave partial state
        if (c == 0) {
#pragma unroll
            for (int r = 0; r < 4; ++r) {
                mlds[wid][g * 4 + r] = m_r[r];
                llds[wid][g * 4 + r] = l_r[r];
            }
        }
#pragma unroll
        for (int dt = 0; dt < 4; ++dt)
#pragma unroll
            for (int r = 0; r < 4; ++r)
                olds[wid][g * 4 + r][dt * 16 + c] = o[dt][r];
        __syncthreads();

        // cross-wave combine
        float* op = out + (size_t)(b * 2048 + qbase) * 64;
#pragma unroll
        for (int i = 0; i < 4; ++i) {
            const int idx = tid + i * 256;        // 0..1023 over (row,d)
            const int row = idx >> 6, d = idx & 63;
            float M = mlds[0][row];
#pragma unroll
            for (int w = 1; w < 4; ++w) M = fmaxf(M, mlds[w][row]);
            float num = 0.f, den = 0.f;
#pragma unroll
            for (int w = 0; w < 4; ++w) {
                const float wt = __expf(mlds[w][row] - M);
                num += wt * olds[w][row][d];
                den += wt * llds[w][row];
            }
            op[row * 64 + d] = num / den;
        }
    }
}

// ======================= fallback: proven R3 kernels =======================
__global__ void wt_kernel(const float* __restrict__ Wq,
                          const float* __restrict__ Wk,
                          const float* __restrict__ Wv,
                          short* __restrict__ Wt) {
    int tid = blockIdx.x * blockDim.x + threadIdx.x;
    int m   = tid >> 15;
    int rem = tid & 32767;
    int d   = rem >> 9;
    int k   = rem & 511;
    const float* W = (m == 0) ? Wq : (m == 1) ? Wk : Wv;
    Wt[tid] = f2bf(W[k * 64 + d]);
}

__global__ __launch_bounds__(64) void proj_kernel(const float* __restrict__ x,
                                                  const short* __restrict__ Wt,
                                                  const float* __restrict__ bq,
                                                  const float* __restrict__ bk,
                                                  const float* __restrict__ bv,
                                                  short* __restrict__ Qb,
                                                  short* __restrict__ Kb,
                                                  short* __restrict__ Vt) {
    const int lane = threadIdx.x;
    const int g = lane >> 4, c = lane & 15;
    const int mat = blockIdx.x % 3;
    const int rowbase = (blockIdx.x / 3) * 16;
    const float* xrow = x + (size_t)(rowbase + c) * 512;
    const short* Wm = Wt + (size_t)mat * 64 * 512;

    fx4 acc[4];
#pragma unroll
    for (int t = 0; t < 4; ++t) acc[t] = (fx4){0.f, 0.f, 0.f, 0.f};

#pragma unroll 4
    for (int ks = 0; ks < 16; ++ks) {
        const int k0 = ks * 32 + g * 8;
        const float4 x0 = *(const float4*)(xrow + k0);
        const float4 x1 = *(const float4*)(xrow + k0 + 4);
        bhalf8 a;
        a[0] = f2bf(x0.x); a[1] = f2bf(x0.y); a[2] = f2bf(x0.z); a[3] = f2bf(x0.w);
        a[4] = f2bf(x1.x); a[5] = f2bf(x1.y); a[6] = f2bf(x1.z); a[7] = f2bf(x1.w);
#pragma unroll
        for (int t = 0; t < 4; ++t) {
            const bhalf8 bf = *(const bhalf8*)(Wm + (size_t)(t * 16 + c) * 512 + k0);
            acc[t] = MFMA(a, bf, acc[t]);
        }
    }

    const float* bias = (mat == 0) ? bq : (mat == 1) ? bk : bv;
#pragma unroll
    for (int t = 0; t < 4; ++t) {
        const int col = t * 16 + c;
        const float bv_ = bias[col];
#pragma unroll
        for (int r = 0; r < 4; ++r) {
            const int row = rowbase + g * 4 + r;
            const short hv = f2bf(acc[t][r] + bv_);
            if (mat == 0)      Qb[row * 64 + col] = hv;
            else if (mat == 1) Kb[row * 64 + col] = hv;
            else               Vt[((size_t)(row >> 11) * 64 + col) * 2048 + (row & 2047)] = hv;
        }
    }
}

__global__ __launch_bounds__(512) void attn_kernel(const short* __restrict__ Qb,
                                                   const short* __restrict__ Kb,
                                                   const short* __restrict__ Vt,
                                                   const int* __restrict__ mask,
                                                   float* __restrict__ out) {
    const int tid  = threadIdx.x;
    const int wid  = tid >> 6;
    const int lane = tid & 63;
    const int g = lane >> 4, c = lane & 15;
    const int b     = blockIdx.x >> 7;
    const int qbase = (blockIdx.x & 127) << 4;
    const short* Qp = Qb + (size_t)(b * 2048 + qbase) * 64;
    const short* Kp = Kb + (size_t)b * 2048 * 64;
    const short* Vp = Vt + (size_t)b * 64 * 2048;
    const int*   mp = mask + b * 2048;

    const bhalf8 qf0 = *(const bhalf8*)(Qp + c * 64 + g * 8);
    const bhalf8 qf1 = *(const bhalf8*)(Qp + c * 64 + 32 + g * 8);

    float m_r[4], l_r[4];
    fx4 o[4];
#pragma unroll
    for (int r = 0; r < 4; ++r) { m_r[r] = -1e30f; l_r[r] = 0.f; }
#pragma unroll
    for (int dt = 0; dt < 4; ++dt) o[dt] = (fx4){0.f, 0.f, 0.f, 0.f};

    __shared__ float olds[8][16][65];
    __shared__ float mlds[8][16];
    __shared__ float llds[8][16];
    __shared__ short Plds[8][16][72];

    for (int kt = 0; kt < 4; ++kt) {
        const int kb = (wid * 4 + kt) * 64;
        fx4 s[4];
#pragma unroll
        for (int t = 0; t < 4; ++t) {
            const short* kp = Kp + (size_t)(kb + t * 16 + c) * 64 + g * 8;
            const bhalf8 kf0 = *(const bhalf8*)(kp);
            const bhalf8 kf1 = *(const bhalf8*)(kp + 32);
            fx4 z = (fx4){0.f, 0.f, 0.f, 0.f};
            z = MFMA(qf0, kf0, z);
            s[t] = MFMA(qf1, kf1, z);
        }
        float madd[4];
#pragma unroll
        for (int t = 0; t < 4; ++t) madd[t] = mp[kb + t * 16 + c] ? 0.f : -1e9f;
        float p[4][4], tm[4];
#pragma unroll
        for (int r = 0; r < 4; ++r) {
            tm[r] = -1e30f;
#pragma unroll
            for (int t = 0; t < 4; ++t) {
                p[t][r] = s[t][r] * 0.125f + madd[t];
                tm[r] = fmaxf(tm[r], p[t][r]);
            }
        }
#pragma unroll
        for (int r = 0; r < 4; ++r) {
            tm[r] = fmaxf(tm[r], __shfl_xor(tm[r], 1));
            tm[r] = fmaxf(tm[r], __shfl_xor(tm[r], 2));
            tm[r] = fmaxf(tm[r], __shfl_xor(tm[r], 4));
            tm[r] = fmaxf(tm[r], __shfl_xor(tm[r], 8));
        }
        float fac[4];
#pragma unroll
        for (int r = 0; r < 4; ++r) {
            const float nm = fmaxf(m_r[r], tm[r]);
            fac[r] = __expf(m_r[r] - nm);
            m_r[r] = nm;
            float rs = 0.f;
#pragma unroll
            for (int t = 0; t < 4; ++t) {
                p[t][r] = __expf(p[t][r] - nm);
                rs += p[t][r];
            }
            rs += __shfl_xor(rs, 1);
            rs += __shfl_xor(rs, 2);
            rs += __shfl_xor(rs, 4);
            rs += __shfl_xor(rs, 8);
            l_r[r] = l_r[r] * fac[r] + rs;
        }
#pragma unroll
        for (int dt = 0; dt < 4; ++dt)
#pragma unroll
            for (int r = 0; r < 4; ++r) o[dt][r] *= fac[r];

        asm volatile("" ::: "memory");
#pragma unroll
        for (int t = 0; t < 4; ++t)
#pragma unroll
            for (int r = 0; r < 4; ++r)
                Plds[wid][g * 4 + r][t * 16 + c] = f2bf(p[t][r]);
        asm volatile("s_waitcnt lgkmcnt(0)" ::: "memory");
        const bhalf8 pa0 = *(const bhalf8*)(&Plds[wid][c][g * 8]);
        const bhalf8 pa1 = *(const bhalf8*)(&Plds[wid][c][32 + g * 8]);
#pragma unroll
        for (int dt = 0; dt < 4; ++dt) {
            const short* vp = Vp + (size_t)(dt * 16 + c) * 2048 + kb + g * 8;
            const bhalf8 vf0 = *(const bhalf8*)(vp);
            const bhalf8 vf1 = *(const bhalf8*)(vp + 32);
            o[dt] = MFMA(pa0, vf0, o[dt]);
            o[dt] = MFMA(pa1, vf1, o[dt]);
        }
    }

    if (c == 0) {
#pragma unroll
        for (int r = 0; r < 4; ++r) {
            mlds[wid][g * 4 + r] = m_r[r];
            llds[wid][g * 4 + r] = l_r[r];
        }
    }
#pragma unroll
    for (int dt = 0; dt < 4; ++dt)
#pragma unroll
        for (int r = 0; r < 4; ++r)
            olds[wid][g * 4 + r][dt * 16 + c] = o[dt][r];
    __syncthreads();

    float* op = out + (size_t)(b * 2048 + qbase) * 64;
#pragma unroll
    for (int i = 0; i < 2; ++i) {
        const int idx = tid + i * 512;
        const int row = idx >> 6, d = idx & 63;
        float M = mlds[0][row];
#pragma unroll
        for (int w = 1; w < 8; ++w) M = fmaxf(M, mlds[w][row]);
        float num = 0.f, den = 0.f;
#pragma unroll
        for (int w = 0; w < 8; ++w) {
            const float wt = __expf(mlds[w][row] - M);
            num += wt * olds[w][row][d];
            den += wt * llds[w][row];
        }
        op[row * 64 + d] = num / den;
    }
}

extern "C" void kernel_launch(void* const* d_in, const int* in_sizes, int n_in,
                              void* d_out, int out_size, void* d_ws, size_t ws_size,
                              hipStream_t stream) {
    const float* x    = (const float*)d_in[0];
    const int*   mask = (const int*)d_in[1];
    const float* Wq   = (const float*)d_in[2];
    const float* bq   = (const float*)d_in[3];
    const float* Wk   = (const float*)d_in[4];
    const float* bk   = (const float*)d_in[5];
    const float* Wv   = (const float*)d_in[6];
    const float* bv   = (const float*)d_in[7];
    float* out = (float*)d_out;

    short* Wt = (short*)d_ws;                 // 3*64*512
    short* Qb = Wt + 3 * 64 * 512;            // 4*2048*64
    short* Kb = Qb + 4 * 2048 * 64;           // 4*2048*64
    short* Vt = Kb + 4 * 2048 * 64;           // 4*2048*64  ([B][64][2048])

    void* args[] = {(void*)&x, (void*)&mask, (void*)&Wq, (void*)&bq,
                    (void*)&Wk, (void*)&bk, (void*)&Wv, (void*)&bv,
                    (void*)&Wt, (void*)&Qb, (void*)&Kb, (void*)&Vt, (void*)&out};
    hipError_t err = hipLaunchCooperativeKernel((void*)mega_kernel, dim3(512),
                                                dim3(256), args, 0, stream);
    if (err != hipSuccess) {
        (void)hipGetLastError();   // clear sticky error, take proven 3-kernel path
        wt_kernel<<<384, 256, 0, stream>>>(Wq, Wk, Wv, Wt);
        proj_kernel<<<1536, 64, 0, stream>>>(x, Wt, bq, bk, bv, Qb, Kb, Vt);
        attn_kernel<<<512, 512, 0, stream>>>(Qb, Kb, Vt, mask, out);
    }
}

// Round 6
// 68.001 us; speedup vs baseline: 3.9752x; 3.9752x over previous
//
#include <hip/hip_runtime.h>

// Fused attention block: B=4, S=2048, F=512, D=64
//  q = x@Wq + bq ; k = x@Wk + bk ; v = x@Wv + bv      (B,S,D)
//  logits = q@k^T / 8 + (1-mask)*-1e9 ; attn = softmax ; out = attn@v
//
// R6: back to 3 kernels (cooperative grid.sync measured at ~100us/sync on
// 8 XCDs -- abandoned). VALU diet:
//  - convert_kernel: x -> bf16 once (proj loses 80 VALU f2bf per k-step x3),
//    fused with W transpose+convert.
//  - attn: P->bf16 via v_cvt_pk_bf16_f32 pairs + ds_write_b64, using a
//    within-64-key PHYSICAL permutation (phys = t + 4*c <-> logical = 16t+c);
//    Vt is written by proj in the same permuted key order, so PV fragment
//    reads stay contiguous. Sum over permuted k is unchanged.
//
// MFMA v_mfma_f32_16x16x32_bf16 fragment layouts (guide §3, m89/m91):
//   A: lane holds A[row = lane&15][k = (lane>>4)*8 + e], e=0..7
//   B: lane holds B[k = (lane>>4)*8 + e][col = lane&15]
//   C/D: lane holds D[row = (lane>>4)*4 + r][col = lane&15], r=0..3

typedef __attribute__((ext_vector_type(8))) short bhalf8;
typedef __attribute__((ext_vector_type(4))) float fx4;

#define MFMA(a, b, c) __builtin_amdgcn_mfma_f32_16x16x32_bf16((a), (b), (c), 0, 0, 0)

__device__ __forceinline__ short f2bf(float f) {
    union { float f; unsigned u; } v; v.f = f;
    unsigned r = (v.u + 0x7FFFu + ((v.u >> 16) & 1u)) >> 16;  // RNE
    return (short)r;
}

__device__ __forceinline__ unsigned cvt_pk_bf16(float lo, float hi) {
    unsigned r;
    asm("v_cvt_pk_bf16_f32 %0, %1, %2" : "=v"(r) : "v"(lo), "v"(hi));
    return r;
}

// ---- Kernel 1: x (f32) -> xb (bf16), W[F][D] f32 -> Wt[3][64][512] bf16 (T) ----
__global__ __launch_bounds__(256) void convert_kernel(
    const float* __restrict__ x,
    const float* __restrict__ Wq, const float* __restrict__ Wk,
    const float* __restrict__ Wv,
    short* __restrict__ xb, short* __restrict__ Wt)
{
    const int gt = blockIdx.x * 256 + threadIdx.x;      // 0..262143
    // xb: 8192*512 = 4194304 elems = 1048576 float4 units, 4 per thread
    const float4* x4 = (const float4*)x;
    uint2* xb2 = (uint2*)xb;
#pragma unroll
    for (int i = 0; i < 4; ++i) {
        const int v = gt + i * 262144;
        const float4 f = x4[v];
        uint2 o;
        o.x = cvt_pk_bf16(f.x, f.y);
        o.y = cvt_pk_bf16(f.z, f.w);
        xb2[v] = o;
    }
    // Wt: 3*64*512 = 98304 elems
    if (gt < 3 * 64 * 512) {
        const int m = gt >> 15, rem = gt & 32767;
        const int d = rem >> 9, k = rem & 511;
        const float* W = (m == 0) ? Wq : (m == 1) ? Wk : Wv;
        Wt[gt] = f2bf(W[k * 64 + d]);
    }
}

// ---- Kernel 2: QKV projection. 4 waves/block x (16 rows, 1 matrix), grid 384 ----
// Outputs: Qb,Kb bf16 [B*S][64]; Vt bf16 [B][64][2048] with within-64-key
// permutation phys = (s>>4 & 3) + (s&15)*4 (matches attn's packed-P layout).
__global__ __launch_bounds__(256) void proj_kernel(
    const short* __restrict__ xb, const short* __restrict__ Wt,
    const float* __restrict__ bq, const float* __restrict__ bk,
    const float* __restrict__ bv,
    short* __restrict__ Qb, short* __restrict__ Kb, short* __restrict__ Vt)
{
    const int lane = threadIdx.x & 63;
    const int wid  = threadIdx.x >> 6;
    const int g = lane >> 4, c = lane & 15;
    const int uid = blockIdx.x * 4 + wid;        // 0..1535
    const int mat = uid % 3;
    const int rowbase = (uid / 3) * 16;
    const short* xrow = xb + (size_t)(rowbase + c) * 512;   // A row = lane&15
    const short* Wm = Wt + (size_t)mat * 64 * 512;

    fx4 acc[4];
#pragma unroll
    for (int t = 0; t < 4; ++t) acc[t] = (fx4){0.f, 0.f, 0.f, 0.f};

#pragma unroll 4
    for (int ks = 0; ks < 16; ++ks) {
        const int k0 = ks * 32 + g * 8;
        const bhalf8 a = *(const bhalf8*)(xrow + k0);
#pragma unroll
        for (int t = 0; t < 4; ++t) {
            const bhalf8 bf = *(const bhalf8*)(Wm + (size_t)(t * 16 + c) * 512 + k0);
            acc[t] = MFMA(a, bf, acc[t]);
        }
    }

    const float* bias = (mat == 0) ? bq : (mat == 1) ? bk : bv;
#pragma unroll
    for (int t = 0; t < 4; ++t) {
        const int col = t * 16 + c;
        const float bv_ = bias[col];
#pragma unroll
        for (int r = 0; r < 4; ++r) {
            const int row = rowbase + g * 4 + r;     // D row = (lane>>4)*4+r
            const short hv = f2bf(acc[t][r] + bv_);
            if (mat == 0)      Qb[row * 64 + col] = hv;
            else if (mat == 1) Kb[row * 64 + col] = hv;
            else {
                const int s = row & 2047, b_ = row >> 11;
                const int sp = (s & ~63) | (((s >> 4) & 3) + (s & 15) * 4);
                Vt[((size_t)b_ * 64 + col) * 2048 + sp] = hv;
            }
        }
    }
}

// ---- Kernel 3: flash attention. 8 waves/block, 16 q-rows/block, per-wave
// 256-key slice (4 iters x 64 keys), private online softmax, LDS combine ----
__global__ __launch_bounds__(512) void attn_kernel(const short* __restrict__ Qb,
                                                   const short* __restrict__ Kb,
                                                   const short* __restrict__ Vt,
                                                   const int* __restrict__ mask,
                                                   float* __restrict__ out) {
    const int tid  = threadIdx.x;
    const int wid  = tid >> 6;
    const int lane = tid & 63;
    const int g = lane >> 4, c = lane & 15;
    const int b     = blockIdx.x >> 7;
    const int qbase = (blockIdx.x & 127) << 4;
    const short* Qp = Qb + (size_t)(b * 2048 + qbase) * 64;
    const short* Kp = Kb + (size_t)b * 2048 * 64;
    const short* Vp = Vt + (size_t)b * 64 * 2048;
    const int*   mp = mask + b * 2048;

    const bhalf8 qf0 = *(const bhalf8*)(Qp + c * 64 + g * 8);
    const bhalf8 qf1 = *(const bhalf8*)(Qp + c * 64 + 32 + g * 8);

    float m_r[4], l_r[4];
    fx4 o[4];
#pragma unroll
    for (int r = 0; r < 4; ++r) { m_r[r] = -1e30f; l_r[r] = 0.f; }
#pragma unroll
    for (int dt = 0; dt < 4; ++dt) o[dt] = (fx4){0.f, 0.f, 0.f, 0.f};

    __shared__ float olds[8][16][65];                 // pad 65: no bank clash
    __shared__ float mlds[8][16];
    __shared__ float llds[8][16];
    __shared__ __align__(16) short Plds[8][16][72];   // pitch 144B = 9x16B

    for (int kt = 0; kt < 4; ++kt) {
        const int kb = (wid * 4 + kt) * 64;
        // ---- QK^T: four 16-key n-tiles, K=64 ----
        fx4 s[4];
#pragma unroll
        for (int t = 0; t < 4; ++t) {
            const short* kp = Kp + (size_t)(kb + t * 16 + c) * 64 + g * 8;
            const bhalf8 kf0 = *(const bhalf8*)(kp);
            const bhalf8 kf1 = *(const bhalf8*)(kp + 32);
            fx4 z = (fx4){0.f, 0.f, 0.f, 0.f};
            z = MFMA(qf0, kf0, z);
            s[t] = MFMA(qf1, kf1, z);
        }
        // ---- mask + scale; online softmax (rows g*4+r, logical cols c+16t) ----
        float madd[4];
#pragma unroll
        for (int t = 0; t < 4; ++t) madd[t] = mp[kb + t * 16 + c] ? 0.f : -1e9f;
        float p[4][4], tm[4];
#pragma unroll
        for (int r = 0; r < 4; ++r) {
            tm[r] = -1e30f;
#pragma unroll
            for (int t = 0; t < 4; ++t) {
                p[t][r] = s[t][r] * 0.125f + madd[t];
                tm[r] = fmaxf(tm[r], p[t][r]);
            }
        }
#pragma unroll
        for (int r = 0; r < 4; ++r) {
            tm[r] = fmaxf(tm[r], __shfl_xor(tm[r], 1));
            tm[r] = fmaxf(tm[r], __shfl_xor(tm[r], 2));
            tm[r] = fmaxf(tm[r], __shfl_xor(tm[r], 4));
            tm[r] = fmaxf(tm[r], __shfl_xor(tm[r], 8));
        }
        float fac[4];
#pragma unroll
        for (int r = 0; r < 4; ++r) {
            const float nm = fmaxf(m_r[r], tm[r]);
            fac[r] = __expf(m_r[r] - nm);
            m_r[r] = nm;
            float rs = 0.f;
#pragma unroll
            for (int t = 0; t < 4; ++t) {
                p[t][r] = __expf(p[t][r] - nm);
                rs += p[t][r];
            }
            rs += __shfl_xor(rs, 1);
            rs += __shfl_xor(rs, 2);
            rs += __shfl_xor(rs, 4);
            rs += __shfl_xor(rs, 8);
            l_r[r] = l_r[r] * fac[r] + rs;
        }
#pragma unroll
        for (int dt = 0; dt < 4; ++dt)
#pragma unroll
            for (int r = 0; r < 4; ++r) o[dt][r] *= fac[r];

        // ---- P -> LDS, packed: phys col = c*4 + t (one b64 per row) ----
        asm volatile("" ::: "memory");
#pragma unroll
        for (int r = 0; r < 4; ++r) {
            uint2 w0;
            w0.x = cvt_pk_bf16(p[0][r], p[1][r]);   // phys cols 4c, 4c+1
            w0.y = cvt_pk_bf16(p[2][r], p[3][r]);   // phys cols 4c+2, 4c+3
            *(uint2*)&Plds[wid][g * 4 + r][c * 4] = w0;
        }
        asm volatile("s_waitcnt lgkmcnt(0)" ::: "memory");
        const bhalf8 pa0 = *(const bhalf8*)(&Plds[wid][c][g * 8]);        // phys k
        const bhalf8 pa1 = *(const bhalf8*)(&Plds[wid][c][32 + g * 8]);
#pragma unroll
        for (int dt = 0; dt < 4; ++dt) {
            const short* vp = Vp + (size_t)(dt * 16 + c) * 2048 + kb + g * 8;
            const bhalf8 vf0 = *(const bhalf8*)(vp);       // Vt is key-permuted
            const bhalf8 vf1 = *(const bhalf8*)(vp + 32);  // to match packed P
            o[dt] = MFMA(pa0, vf0, o[dt]);
            o[dt] = MFMA(pa1, vf1, o[dt]);
        }
    }

    // ---- publish per-wave partial state ----
    if (c == 0) {
#pragma unroll
        for (int r = 0; r < 4; ++r) {
            mlds[wid][g * 4 + r] = m_r[r];
            llds[wid][g * 4 + r] = l_r[r];
        }
    }
#pragma unroll
    for (int dt = 0; dt < 4; ++dt)
#pragma unroll
        for (int r = 0; r < 4; ++r)
            olds[wid][g * 4 + r][dt * 16 + c] = o[dt][r];
    __syncthreads();

    // ---- cross-wave combine ----
    float* op = out + (size_t)(b * 2048 + qbase) * 64;
#pragma unroll
    for (int i = 0; i < 2; ++i) {
        const int idx = tid + i * 512;        // 0..1023 over (row,d)
        const int row = idx >> 6, d = idx & 63;
        float M = mlds[0][row];
#pragma unroll
        for (int w = 1; w < 8; ++w) M = fmaxf(M, mlds[w][row]);
        float num = 0.f, den = 0.f;
#pragma unroll
        for (int w = 0; w < 8; ++w) {
            const float wt = __expf(mlds[w][row] - M);
            num += wt * olds[w][row][d];
            den += wt * llds[w][row];
        }
        op[row * 64 + d] = num / den;
    }
}

extern "C" void kernel_launch(void* const* d_in, const int* in_sizes, int n_in,
                              void* d_out, int out_size, void* d_ws, size_t ws_size,
                              hipStream_t stream) {
    const float* x    = (const float*)d_in[0];
    const int*   mask = (const int*)d_in[1];
    const float* Wq   = (const float*)d_in[2];
    const float* bq   = (const float*)d_in[3];
    const float* Wk   = (const float*)d_in[4];
    const float* bk   = (const float*)d_in[5];
    const float* Wv   = (const float*)d_in[6];
    const float* bv   = (const float*)d_in[7];
    float* out = (float*)d_out;

    short* xb = (short*)d_ws;                 // 8192*512 bf16 (8.4 MB)
    short* Wt = xb + 8192 * 512;              // 3*64*512
    short* Qb = Wt + 3 * 64 * 512;            // 4*2048*64
    short* Kb = Qb + 4 * 2048 * 64;           // 4*2048*64
    short* Vt = Kb + 4 * 2048 * 64;           // 4*2048*64 ([B][64][2048], key-permuted)

    convert_kernel<<<1024, 256, 0, stream>>>(x, Wq, Wk, Wv, xb, Wt);
    proj_kernel<<<384, 256, 0, stream>>>(xb, Wt, bq, bk, bv, Qb, Kb, Vt);
    attn_kernel<<<512, 512, 0, stream>>>(Qb, Kb, Vt, mask, out);
}

// Round 8
// 54.774 us; speedup vs baseline: 4.9351x; 1.2415x over previous
//
#include <hip/hip_runtime.h>

// Fused attention block: B=4, S=2048, F=512, D=64
//  q = x@Wq + bq ; k = x@Wk + bk ; v = x@Wv + bv      (B,S,D)
//  logits = q@k^T / 8 + (1-mask)*-1e9 ; attn = softmax ; out = attn@v
//
// R8: R7's 2-kernel structure with the attn LDS ordering fences RESTORED.
// R7 removed them and failed (absmax 1.9e9): the P round-trip is a
// CROSS-LANE LDS exchange (lane writes rows g*4+r, reads row c); per-thread
// alias analysis sees disjoint addresses for most lanes, so the compiler
// reordered ds_read before ds_write. The asm pair (compiler memory fence +
// lgkmcnt(0)) is what makes the intra-wave exchange safe -- keep it.
//
// MFMA v_mfma_f32_16x16x32_bf16 fragment layouts (guide §3, m89/m91):
//   A: lane holds A[row = lane&15][k = (lane>>4)*8 + e], e=0..7
//   B: lane holds B[k = (lane>>4)*8 + e][col = lane&15]
//   C/D: lane holds D[row = (lane>>4)*4 + r][col = lane&15], r=0..3

typedef __attribute__((ext_vector_type(8))) short bhalf8;
typedef __attribute__((ext_vector_type(4))) float fx4;

#define MFMA(a, b, c) __builtin_amdgcn_mfma_f32_16x16x32_bf16((a), (b), (c), 0, 0, 0)

__device__ __forceinline__ short f2bf(float f) {
    union { float f; unsigned u; } v; v.f = f;
    unsigned r = (v.u + 0x7FFFu + ((v.u >> 16) & 1u)) >> 16;  // RNE
    return (short)r;
}

__device__ __forceinline__ unsigned cvt_pk_bf16(float lo, float hi) {
    unsigned r;
    asm("v_cvt_pk_bf16_f32 %0, %1, %2" : "=v"(r) : "v"(lo), "v"(hi));
    return r;
}

// Build B-fragment B[k0+e][col] (e=0..7) from row-major f32 W[512][64].
// 8 coalesced dword loads (16 lanes x consecutive cols) + 4 cvt_pk.
__device__ __forceinline__ bhalf8 wfrag(const float* __restrict__ W, int k0, int col) {
    union { unsigned u[4]; bhalf8 h; } r;
#pragma unroll
    for (int e2 = 0; e2 < 4; ++e2)
        r.u[e2] = cvt_pk_bf16(W[(k0 + 2 * e2) * 64 + col],
                              W[(k0 + 2 * e2 + 1) * 64 + col]);
    return r.h;
}

// ---- Kernel 1: QKV projection, conversion fused. 512 blocks x 256 thr ----
// Block = 16 x-rows (staged f32->bf16 in LDS); wave w = col-quarter w*16..+15
// for ALL of Q,K,V. Outputs: Qb,Kb bf16 [B*S][64]; Vt bf16 [B][64][2048]
// with within-64-key permutation phys = ((s>>4)&3) + (s&15)*4 (matches
// attn's packed-P physical layout).
__global__ __launch_bounds__(256) void proj_kernel(
    const float* __restrict__ x,
    const float* __restrict__ Wq, const float* __restrict__ bq,
    const float* __restrict__ Wk, const float* __restrict__ bk,
    const float* __restrict__ Wv, const float* __restrict__ bv,
    short* __restrict__ Qb, short* __restrict__ Kb, short* __restrict__ Vt)
{
    const int tid  = threadIdx.x;
    const int lane = tid & 63;
    const int wid  = tid >> 6;              // col-quarter 0..3
    const int g = lane >> 4, c = lane & 15;
    const int rowbase = blockIdx.x * 16;

    __shared__ __align__(16) short xs[16][520];   // pitch 1040B: 8 lanes per
                                                  // 4-bank window = LDS BW peak

    // ---- stage x rows -> bf16 LDS (coalesced float4, cvt_pk, 16B writes) ----
#pragma unroll
    for (int i = 0; i < 4; ++i) {
        const int id  = tid + i * 256;       // 0..1023 over (row, col-chunk)
        const int row = id >> 6;
        const int col8 = (id & 63) * 8;
        const float* xp = x + (size_t)(rowbase + row) * 512 + col8;
        const float4 f0 = *(const float4*)(xp);
        const float4 f1 = *(const float4*)(xp + 4);
        union { unsigned u[4]; uint4 v; } wv;
        wv.u[0] = cvt_pk_bf16(f0.x, f0.y);
        wv.u[1] = cvt_pk_bf16(f0.z, f0.w);
        wv.u[2] = cvt_pk_bf16(f1.x, f1.y);
        wv.u[3] = cvt_pk_bf16(f1.z, f1.w);
        *(uint4*)&xs[row][col8] = wv.v;
    }
    __syncthreads();

    const int col = wid * 16 + c;
    fx4 aq = (fx4){0.f, 0.f, 0.f, 0.f};
    fx4 ak = (fx4){0.f, 0.f, 0.f, 0.f};
    fx4 av = (fx4){0.f, 0.f, 0.f, 0.f};

#pragma unroll 4
    for (int ks = 0; ks < 16; ++ks) {
        const int k0 = ks * 32 + g * 8;
        const bhalf8 a = *(const bhalf8*)&xs[c][k0];   // A row = lane&15
        aq = MFMA(a, wfrag(Wq, k0, col), aq);
        ak = MFMA(a, wfrag(Wk, k0, col), ak);
        av = MFMA(a, wfrag(Wv, k0, col), av);
    }

    const float bq_ = bq[col], bk_ = bk[col], bv_ = bv[col];
#pragma unroll
    for (int r = 0; r < 4; ++r) {
        const int row = rowbase + g * 4 + r;           // D row = (lane>>4)*4+r
        Qb[row * 64 + col] = f2bf(aq[r] + bq_);
        Kb[row * 64 + col] = f2bf(ak[r] + bk_);
        const int s = row & 2047, b_ = row >> 11;
        const int sp = (s & ~63) | (((s >> 4) & 3) + (s & 15) * 4);
        Vt[((size_t)b_ * 64 + col) * 2048 + sp] = f2bf(av[r] + bv_);
    }
}

// ---- Kernel 2: flash attention. 8 waves/block, 16 q-rows/block, per-wave
// 256-key slice (4 iters x 64 keys), private online softmax, LDS combine ----
__global__ __launch_bounds__(512) void attn_kernel(const short* __restrict__ Qb,
                                                   const short* __restrict__ Kb,
                                                   const short* __restrict__ Vt,
                                                   const int* __restrict__ mask,
                                                   float* __restrict__ out) {
    const int tid  = threadIdx.x;
    const int wid  = tid >> 6;
    const int lane = tid & 63;
    const int g = lane >> 4, c = lane & 15;
    const int b     = blockIdx.x >> 7;
    const int qbase = (blockIdx.x & 127) << 4;
    const short* Qp = Qb + (size_t)(b * 2048 + qbase) * 64;
    const short* Kp = Kb + (size_t)b * 2048 * 64;
    const short* Vp = Vt + (size_t)b * 64 * 2048;
    const int*   mp = mask + b * 2048;

    const bhalf8 qf0 = *(const bhalf8*)(Qp + c * 64 + g * 8);
    const bhalf8 qf1 = *(const bhalf8*)(Qp + c * 64 + 32 + g * 8);

    float m_r[4], l_r[4];
    fx4 o[4];
#pragma unroll
    for (int r = 0; r < 4; ++r) { m_r[r] = -1e30f; l_r[r] = 0.f; }
#pragma unroll
    for (int dt = 0; dt < 4; ++dt) o[dt] = (fx4){0.f, 0.f, 0.f, 0.f};

    __shared__ float olds[8][16][65];                 // pad 65: no bank clash
    __shared__ float mlds[8][16];
    __shared__ float llds[8][16];
    __shared__ __align__(16) short Plds[8][16][72];   // pitch 144B = 9x16B

    for (int kt = 0; kt < 4; ++kt) {
        const int kb = (wid * 4 + kt) * 64;
        // ---- QK^T: four 16-key n-tiles, K=64 ----
        fx4 s[4];
#pragma unroll
        for (int t = 0; t < 4; ++t) {
            const short* kp = Kp + (size_t)(kb + t * 16 + c) * 64 + g * 8;
            const bhalf8 kf0 = *(const bhalf8*)(kp);
            const bhalf8 kf1 = *(const bhalf8*)(kp + 32);
            fx4 z = (fx4){0.f, 0.f, 0.f, 0.f};
            z = MFMA(qf0, kf0, z);
            s[t] = MFMA(qf1, kf1, z);
        }
        // ---- mask + scale; online softmax (rows g*4+r, logical cols c+16t) ----
        float madd[4];
#pragma unroll
        for (int t = 0; t < 4; ++t) madd[t] = mp[kb + t * 16 + c] ? 0.f : -1e9f;
        float p[4][4], tm[4];
#pragma unroll
        for (int r = 0; r < 4; ++r) {
            tm[r] = -1e30f;
#pragma unroll
            for (int t = 0; t < 4; ++t) {
                p[t][r] = s[t][r] * 0.125f + madd[t];
                tm[r] = fmaxf(tm[r], p[t][r]);
            }
        }
#pragma unroll
        for (int r = 0; r < 4; ++r) {
            tm[r] = fmaxf(tm[r], __shfl_xor(tm[r], 1));
            tm[r] = fmaxf(tm[r], __shfl_xor(tm[r], 2));
            tm[r] = fmaxf(tm[r], __shfl_xor(tm[r], 4));
            tm[r] = fmaxf(tm[r], __shfl_xor(tm[r], 8));
        }
        float fac[4];
#pragma unroll
        for (int r = 0; r < 4; ++r) {
            const float nm = fmaxf(m_r[r], tm[r]);
            fac[r] = __expf(m_r[r] - nm);
            m_r[r] = nm;
            float rs = 0.f;
#pragma unroll
            for (int t = 0; t < 4; ++t) {
                p[t][r] = __expf(p[t][r] - nm);
                rs += p[t][r];
            }
            rs += __shfl_xor(rs, 1);
            rs += __shfl_xor(rs, 2);
            rs += __shfl_xor(rs, 4);
            rs += __shfl_xor(rs, 8);
            l_r[r] = l_r[r] * fac[r] + rs;
        }
#pragma unroll
        for (int dt = 0; dt < 4; ++dt)
#pragma unroll
            for (int r = 0; r < 4; ++r) o[dt][r] *= fac[r];

        // ---- P -> LDS, packed: phys col = c*4 + t (one b64 per row) ----
        // CROSS-LANE exchange: the asm pair below is load-bearing (R7 lesson).
        asm volatile("" ::: "memory");
#pragma unroll
        for (int r = 0; r < 4; ++r) {
            uint2 w0;
            w0.x = cvt_pk_bf16(p[0][r], p[1][r]);   // phys cols 4c, 4c+1
            w0.y = cvt_pk_bf16(p[2][r], p[3][r]);   // phys cols 4c+2, 4c+3
            *(uint2*)&Plds[wid][g * 4 + r][c * 4] = w0;
        }
        asm volatile("s_waitcnt lgkmcnt(0)" ::: "memory");
        const bhalf8 pa0 = *(const bhalf8*)(&Plds[wid][c][g * 8]);        // phys k
        const bhalf8 pa1 = *(const bhalf8*)(&Plds[wid][c][32 + g * 8]);
#pragma unroll
        for (int dt = 0; dt < 4; ++dt) {
            const short* vp = Vp + (size_t)(dt * 16 + c) * 2048 + kb + g * 8;
            const bhalf8 vf0 = *(const bhalf8*)(vp);       // Vt is key-permuted
            const bhalf8 vf1 = *(const bhalf8*)(vp + 32);  // to match packed P
            o[dt] = MFMA(pa0, vf0, o[dt]);
            o[dt] = MFMA(pa1, vf1, o[dt]);
        }
    }

    // ---- publish per-wave partial state ----
    if (c == 0) {
#pragma unroll
        for (int r = 0; r < 4; ++r) {
            mlds[wid][g * 4 + r] = m_r[r];
            llds[wid][g * 4 + r] = l_r[r];
        }
    }
#pragma unroll
    for (int dt = 0; dt < 4; ++dt)
#pragma unroll
        for (int r = 0; r < 4; ++r)
            olds[wid][g * 4 + r][dt * 16 + c] = o[dt][r];
    __syncthreads();

    // ---- cross-wave combine ----
    float* op = out + (size_t)(b * 2048 + qbase) * 64;
#pragma unroll
    for (int i = 0; i < 2; ++i) {
        const int idx = tid + i * 512;        // 0..1023 over (row,d)
        const int row = idx >> 6, d = idx & 63;
        float M = mlds[0][row];
#pragma unroll
        for (int w = 1; w < 8; ++w) M = fmaxf(M, mlds[w][row]);
        float num = 0.f, den = 0.f;
#pragma unroll
        for (int w = 0; w < 8; ++w) {
            const float wt = __expf(mlds[w][row] - M);
            num += wt * olds[w][row][d];
            den += wt * llds[w][row];
        }
        op[row * 64 + d] = num / den;
    }
}

extern "C" void kernel_launch(void* const* d_in, const int* in_sizes, int n_in,
                              void* d_out, int out_size, void* d_ws, size_t ws_size,
                              hipStream_t stream) {
    const float* x    = (const float*)d_in[0];
    const int*   mask = (const int*)d_in[1];
    const float* Wq   = (const float*)d_in[2];
    const float* bq   = (const float*)d_in[3];
    const float* Wk   = (const float*)d_in[4];
    const float* bk   = (const float*)d_in[5];
    const float* Wv   = (const float*)d_in[6];
    const float* bv   = (const float*)d_in[7];
    float* out = (float*)d_out;

    short* Qb = (short*)d_ws;                 // 4*2048*64
    short* Kb = Qb + 4 * 2048 * 64;           // 4*2048*64
    short* Vt = Kb + 4 * 2048 * 64;           // 4*2048*64 ([B][64][2048], key-permuted)

    proj_kernel<<<512, 256, 0, stream>>>(x, Wq, bq, Wk, bk, Wv, bv, Qb, Kb, Vt);
    attn_kernel<<<512, 512, 0, stream>>>(Qb, Kb, Vt, mask, out);
}